// Round 8
// baseline (193.692 us; speedup 1.0000x reference)
//
#include <hip/hip_runtime.h>

#define MD 4
#define DD 9          // 2*MD+1
#define KK 81         // DD*DD
#define B_ 4
#define C_ 128
#define H_ 192
#define W_ 192
#define HW (H_ * W_)
#define NWG 2304      // 3 xt * 192 y * 4 b   (all 128 ch per block)
#define PER_XCD (NWG / 8)

// out[b,c,y,x] = (1/C) * sum_{p,o} first[b,p*9+o,y,x] * second[b,c,y+p-4,x+o-4]
//
// Round 8: x-run register dataflow. Rounds 5-7 proved the compiler undoes any
// 2-group software pipeline once register pressure drops (VGPR 72->60/64/64,
// VALUBusy 39->27%, 90.6->127-134us): a float4 feeding one tight 36-FMA group
// can always be deferred to its use. Fix the DATAFLOW, not the schedule:
// each thread computes an 8-wide x-run x 4 channels. Per (p,ch) it loads a
// 16-float window (4 aligned float4) consumed by 72 FMAs across the whole
// o-loop -> loads cannot sink; latency exposed once per ~150 issue cycles.
//   - FMA:load = 18:1 (was 12:1); L1-side volume 2.04 -> 1.36 GB.
//   - fo LDS reads: 2x b128 per (p,o) serve 32 FMA (1:16), 8-way broadcast.
//   - Edges: weights zeroed at LDS-stage time (proven r5-7, absmax same);
//     window loads clamped in-bounds (garbage * 0 = correct).
// Block: 256 thr = 8 xr (8 px) x 32 cg (4 ch). Grid 2304, XCD-swizzled
// y-fastest. Spill sentinel: WRITE_SIZE must stay == 73728 KB.

__global__ __launch_bounds__(256, 1)
void corr_transpose_kernel(const float* __restrict__ first,
                           const float* __restrict__ second,
                           float* __restrict__ out) {
  __shared__ __align__(16) float ldsF[KK * 64];

  // bijective XCD swizzle (2304 % 8 == 0), y-fastest within an XCD chunk
  const int lin = blockIdx.x;
  const int wid = (lin & 7) * PER_XCD + (lin >> 3);
  const int y   = wid % H_;
  const int t   = wid / H_;          // 0..11
  const int xt0 = (t % 3) * 64;
  const int b   = t / 3;

  const int tid = threadIdx.x;

  // ---- stage first[b,:,y,xt0..+63] into LDS with X-edge weight masking ----
  {
    const float* fbase = first + ((size_t)(b * KK) * H_ + y) * (size_t)W_ + xt0;
    const bool edge = (xt0 != 64);     // block-uniform
    for (int idx = tid; idx < KK * 16; idx += 256) {
      const int k  = idx >> 4;
      const int xi = (idx & 15) << 2;
      float4 v = *reinterpret_cast<const float4*>(fbase + (size_t)k * HW + xi);
      if (edge) {
        const int o    = k % DD;
        const int base = xt0 + xi + o - MD;   // second-x for component 0
        if (base + 0 < 0 || base + 0 >= W_) v.x = 0.f;
        if (base + 1 < 0 || base + 1 >= W_) v.y = 0.f;
        if (base + 2 < 0 || base + 2 >= W_) v.z = 0.f;
        if (base + 3 < 0 || base + 3 >= W_) v.w = 0.f;
      }
      *reinterpret_cast<float4*>(&ldsF[k * 64 + xi]) = v;
    }
  }

  const int xr = tid & 7;            // 8 x-runs of 8 pixels
  const int cg = tid >> 3;           // 0..31, 4 channels each
  const int x0 = xt0 + xr * 8;
  const int c0 = cg * 4;

  // window float4 start offsets (in floats), clamped in-bounds.
  // OOB float4s are whole (offsets are multiples of 4) and their weights are
  // zeroed in LDS, so clamped data is harmless.
  int off0 = x0 - 4, off1 = x0, off2 = x0 + 4, off3 = x0 + 8;
  if (off0 < 0) off0 = 0;                  // xt0==0, xr==0
  if (off3 > W_ - 4) off3 = W_ - 4;        // xt0==128, xr==7

  // p-loop bounds hoisted (block-uniform)
  const int pstart = (y >= MD) ? 0 : (MD - y);
  const int pend   = (y + MD < H_) ? DD : (H_ + MD - y);
  const int yy0    = y + pstart - MD;

  const float* secB = second + (size_t)b * C_ * HW;
  const float* rp0 = secB + ((size_t)(c0 + 0) * H_ + yy0) * (size_t)W_;
  const float* rp1 = rp0 + HW;
  const float* rp2 = rp1 + HW;
  const float* rp3 = rp2 + HW;

  __syncthreads();

  float acc0[8], acc1[8], acc2[8], acc3[8];
#pragma unroll
  for (int j = 0; j < 8; ++j) { acc0[j] = 0.f; acc1[j] = 0.f; acc2[j] = 0.f; acc3[j] = 0.f; }

  for (int p = pstart; p < pend; ++p) {
    // 16-float windows per channel: second[c, yy, x0-4 .. x0+11]
    float w0[16], w1[16], w2[16], w3[16];
    *reinterpret_cast<float4*>(&w0[0])  = *reinterpret_cast<const float4*>(rp0 + off0);
    *reinterpret_cast<float4*>(&w0[4])  = *reinterpret_cast<const float4*>(rp0 + off1);
    *reinterpret_cast<float4*>(&w0[8])  = *reinterpret_cast<const float4*>(rp0 + off2);
    *reinterpret_cast<float4*>(&w0[12]) = *reinterpret_cast<const float4*>(rp0 + off3);
    *reinterpret_cast<float4*>(&w1[0])  = *reinterpret_cast<const float4*>(rp1 + off0);
    *reinterpret_cast<float4*>(&w1[4])  = *reinterpret_cast<const float4*>(rp1 + off1);
    *reinterpret_cast<float4*>(&w1[8])  = *reinterpret_cast<const float4*>(rp1 + off2);
    *reinterpret_cast<float4*>(&w1[12]) = *reinterpret_cast<const float4*>(rp1 + off3);
    *reinterpret_cast<float4*>(&w2[0])  = *reinterpret_cast<const float4*>(rp2 + off0);
    *reinterpret_cast<float4*>(&w2[4])  = *reinterpret_cast<const float4*>(rp2 + off1);
    *reinterpret_cast<float4*>(&w2[8])  = *reinterpret_cast<const float4*>(rp2 + off2);
    *reinterpret_cast<float4*>(&w2[12]) = *reinterpret_cast<const float4*>(rp2 + off3);
    *reinterpret_cast<float4*>(&w3[0])  = *reinterpret_cast<const float4*>(rp3 + off0);
    *reinterpret_cast<float4*>(&w3[4])  = *reinterpret_cast<const float4*>(rp3 + off1);
    *reinterpret_cast<float4*>(&w3[8])  = *reinterpret_cast<const float4*>(rp3 + off2);
    *reinterpret_cast<float4*>(&w3[12]) = *reinterpret_cast<const float4*>(rp3 + off3);

#pragma unroll
    for (int o = 0; o < DD; ++o) {
      // first[p*9+o, y, x0..x0+7]: 8-way broadcast across cg, 2-way banks
      float fo8[8];
      *reinterpret_cast<float4*>(&fo8[0]) =
          *reinterpret_cast<const float4*>(&ldsF[(p * DD + o) * 64 + xr * 8]);
      *reinterpret_cast<float4*>(&fo8[4]) =
          *reinterpret_cast<const float4*>(&ldsF[(p * DD + o) * 64 + xr * 8 + 4]);
#pragma unroll
      for (int j = 0; j < 8; ++j) {
        acc0[j] = fmaf(fo8[j], w0[j + o], acc0[j]);
        acc1[j] = fmaf(fo8[j], w1[j + o], acc1[j]);
        acc2[j] = fmaf(fo8[j], w2[j + o], acc2[j]);
        acc3[j] = fmaf(fo8[j], w3[j + o], acc3[j]);
      }
    }

    rp0 += W_; rp1 += W_; rp2 += W_; rp3 += W_;
  }

  const float inv_c = 1.0f / (float)C_;
  float* outB = out + (size_t)b * C_ * HW + (size_t)y * W_ + x0;
#define STORE_CH(ACC, CI)                                                     \
  {                                                                           \
    float4 v;                                                                 \
    v.x = ACC[0] * inv_c; v.y = ACC[1] * inv_c;                               \
    v.z = ACC[2] * inv_c; v.w = ACC[3] * inv_c;                               \
    *reinterpret_cast<float4*>(outB + (size_t)(c0 + CI) * HW) = v;            \
    v.x = ACC[4] * inv_c; v.y = ACC[5] * inv_c;                               \
    v.z = ACC[6] * inv_c; v.w = ACC[7] * inv_c;                               \
    *reinterpret_cast<float4*>(outB + (size_t)(c0 + CI) * HW + 4) = v;        \
  }
  STORE_CH(acc0, 0)
  STORE_CH(acc1, 1)
  STORE_CH(acc2, 2)
  STORE_CH(acc3, 3)
#undef STORE_CH
}

extern "C" void kernel_launch(void* const* d_in, const int* in_sizes, int n_in,
                              void* d_out, int out_size, void* d_ws, size_t ws_size,
                              hipStream_t stream) {
  const float* first  = (const float*)d_in[0];
  const float* second = (const float*)d_in[1];
  float* out = (float*)d_out;

  corr_transpose_kernel<<<dim3(NWG), 256, 0, stream>>>(first, second, out);
}

// Round 9
// 125.888 us; speedup vs baseline: 1.5386x; 1.5386x over previous
//
#include <hip/hip_runtime.h>

#define MD 4
#define DD 9          // 2*MD+1
#define KK 81         // DD*DD
#define B_ 4
#define C_ 128
#define H_ 192
#define W_ 192
#define HW (H_ * W_)
#define NWG 4608      // 2 chalf * 3 xt * 192 y * 4 b
#define PER_XCD (NWG / 8)

// out[b,c,y,x] = (1/C) * sum_{p,o} first[b,p*9+o,y,x] * second[b,c,y+p-4,x+o-4]
//
// Round 9 = round-6 body + amdgpu_waves_per_eu(2,4).
// ROOT CAUSE of rounds 5-8: the pre-RA scheduler targets the LDS-derived
// occupancy (20.5KB -> 7 blocks/CU -> 7 waves/SIMD -> ~72-VGPR budget) and
// sinks any prefetch that exceeds it. Evidence: (256,4)->VGPR 64,
// (256,2)->128, (256,1)->60..72 across FOUR different source structures;
// every "improvement" that shrank live ranges let it compress further and
// collapse the software pipeline (VALUBusy 39->13..29%).
// waves_per_eu(2,4) caps the TARGET at 4 waves/EU (~128-VGPR budget): the
// pipeline live set (12 in-flight float4 windows 48 + fo 36 + acc 16 + addr
// ~16 = ~116) fits BY POLICY, with 4 waves/SIMD of TLP remaining.
// Failure signature to watch: VGPR_Count <= 72 => attribute didn't take.
// Spill sentinel: WRITE_SIZE must stay == 73728 KB.

__device__ __forceinline__ void unpack12(float (&s)[12],
                                         const float4& A, const float4& M,
                                         const float4& E) {
  s[0] = A.x; s[1] = A.y; s[2]  = A.z; s[3]  = A.w;
  s[4] = M.x; s[5] = M.y; s[6]  = M.z; s[7]  = M.w;
  s[8] = E.x; s[9] = E.y; s[10] = E.z; s[11] = E.w;
}

#define FMA_GROUP(accp, s)                                   \
  _Pragma("unroll")                                          \
  for (int o = 0; o < DD; ++o) {                             \
    accp[0] = fmaf(fo[o].x, s[o + 0], accp[0]);              \
    accp[1] = fmaf(fo[o].y, s[o + 1], accp[1]);              \
    accp[2] = fmaf(fo[o].z, s[o + 2], accp[2]);              \
    accp[3] = fmaf(fo[o].w, s[o + 3], accp[3]);              \
  }

__global__ __launch_bounds__(256)
__attribute__((amdgpu_waves_per_eu(2, 4)))
void corr_transpose_kernel(const float* __restrict__ first,
                           const float* __restrict__ second,
                           float* __restrict__ out) {
  __shared__ __align__(16) float ldsF[KK * 64];

  // bijective XCD swizzle (4608 % 8 == 0), y-fastest within an XCD chunk
  const int lin = blockIdx.x;
  const int wid = (lin & 7) * PER_XCD + (lin >> 3);
  const int y     = wid % H_;
  const int t     = wid / H_;          // 0..23
  const int chalf = t & 1;
  const int xt0   = ((t >> 1) % 3) * 64;
  const int b     = t / 6;

  const int tid = threadIdx.x;

  // ---- stage first[b,:,y,xt0..+63] into LDS with X-edge weight masking ----
  {
    const float* fbase = first + ((size_t)(b * KK) * H_ + y) * (size_t)W_ + xt0;
    const bool edge = (xt0 != 64);     // block-uniform
    for (int idx = tid; idx < KK * 16; idx += 256) {
      const int k  = idx >> 4;
      const int xi = (idx & 15) << 2;
      float4 v = *reinterpret_cast<const float4*>(fbase + (size_t)k * HW + xi);
      if (edge) {
        const int o    = k % DD;
        const int base = xt0 + xi + o - MD;   // second-x for component 0
        if (base + 0 < 0 || base + 0 >= W_) v.x = 0.f;
        if (base + 1 < 0 || base + 1 >= W_) v.y = 0.f;
        if (base + 2 < 0 || base + 2 >= W_) v.z = 0.f;
        if (base + 3 < 0 || base + 3 >= W_) v.w = 0.f;
      }
      *reinterpret_cast<float4*>(&ldsF[k * 64 + xi]) = v;
    }
  }

  const int xg = tid & 15;
  const int cg = tid >> 4;
  const int c0 = chalf * 64 + cg * 4;
  const int x0 = xt0 + xg * 4;

  // clamped per-lane offsets; OOB float4s have zeroed weights in LDS
  const bool mA = (x0 != 0);
  const bool mE = (x0 + 8 <= W_);
  const int  oa = mA ? x0 - 4 : 0;
  const int  oe = mE ? x0 + 4 : W_ - 8;

  // p-loop bounds hoisted (block-uniform)
  const int pstart = (y >= MD) ? 0 : (MD - y);
  const int pend   = (y + MD < H_) ? DD : (H_ + MD - y);
  const int yy0    = y + pstart - MD;

  const float* secB = second + (size_t)b * C_ * HW;
  const float* rp0 = secB + ((size_t)c0 * H_ + yy0) * (size_t)W_;
  const float* rp1 = rp0 + HW;
  const float* rp2 = rp1 + HW;
  const float* rp3 = rp2 + HW;

  // prologue: group-0 loads in flight while LDS staging drains
  float4 gA0 = *reinterpret_cast<const float4*>(rp0 + oa);
  float4 gM0 = *reinterpret_cast<const float4*>(rp0 + x0);
  float4 gE0 = *reinterpret_cast<const float4*>(rp0 + oe);
  float4 gA1 = *reinterpret_cast<const float4*>(rp1 + oa);
  float4 gM1 = *reinterpret_cast<const float4*>(rp1 + x0);
  float4 gE1 = *reinterpret_cast<const float4*>(rp1 + oe);

  __syncthreads();

  float acc0[4] = {0.f, 0.f, 0.f, 0.f};
  float acc1[4] = {0.f, 0.f, 0.f, 0.f};
  float acc2[4] = {0.f, 0.f, 0.f, 0.f};
  float acc3[4] = {0.f, 0.f, 0.f, 0.f};

  for (int p = pstart; p < pend; ++p) {
    float4 fo[DD];
#pragma unroll
    for (int o = 0; o < DD; ++o)
      fo[o] = *reinterpret_cast<const float4*>(&ldsF[(p * DD + o) * 64 + (xg << 2)]);

    // issue group-1 loads (current p) before consuming group 0
    float4 hA0 = *reinterpret_cast<const float4*>(rp2 + oa);
    float4 hM0 = *reinterpret_cast<const float4*>(rp2 + x0);
    float4 hE0 = *reinterpret_cast<const float4*>(rp2 + oe);
    float4 hA1 = *reinterpret_cast<const float4*>(rp3 + oa);
    float4 hM1 = *reinterpret_cast<const float4*>(rp3 + x0);
    float4 hE1 = *reinterpret_cast<const float4*>(rp3 + oe);

    {  // FMA group 0 (channels c0, c0+1)
      float s[12];
      unpack12(s, gA0, gM0, gE0);
      FMA_GROUP(acc0, s);
      float u[12];
      unpack12(u, gA1, gM1, gE1);
      FMA_GROUP(acc1, u);
    }

    // advance rows (clamped on last iter: dead but in-bounds reload)
    const int adv = (p + 1 < pend) ? W_ : 0;
    rp0 += adv; rp1 += adv; rp2 += adv; rp3 += adv;

    // prefetch group-0 for next p
    gA0 = *reinterpret_cast<const float4*>(rp0 + oa);
    gM0 = *reinterpret_cast<const float4*>(rp0 + x0);
    gE0 = *reinterpret_cast<const float4*>(rp0 + oe);
    gA1 = *reinterpret_cast<const float4*>(rp1 + oa);
    gM1 = *reinterpret_cast<const float4*>(rp1 + x0);
    gE1 = *reinterpret_cast<const float4*>(rp1 + oe);

    {  // FMA group 1 (channels c0+2, c0+3)
      float s[12];
      unpack12(s, hA0, hM0, hE0);
      FMA_GROUP(acc2, s);
      float u[12];
      unpack12(u, hA1, hM1, hE1);
      FMA_GROUP(acc3, u);
    }
  }

  const float inv_c = 1.0f / (float)C_;
  float* outB = out + (size_t)b * C_ * HW + (size_t)y * W_ + x0;
  {
    float4 v;
    v.x = acc0[0] * inv_c; v.y = acc0[1] * inv_c;
    v.z = acc0[2] * inv_c; v.w = acc0[3] * inv_c;
    *reinterpret_cast<float4*>(outB + (size_t)(c0 + 0) * HW) = v;
    v.x = acc1[0] * inv_c; v.y = acc1[1] * inv_c;
    v.z = acc1[2] * inv_c; v.w = acc1[3] * inv_c;
    *reinterpret_cast<float4*>(outB + (size_t)(c0 + 1) * HW) = v;
    v.x = acc2[0] * inv_c; v.y = acc2[1] * inv_c;
    v.z = acc2[2] * inv_c; v.w = acc2[3] * inv_c;
    *reinterpret_cast<float4*>(outB + (size_t)(c0 + 2) * HW) = v;
    v.x = acc3[0] * inv_c; v.y = acc3[1] * inv_c;
    v.z = acc3[2] * inv_c; v.w = acc3[3] * inv_c;
    *reinterpret_cast<float4*>(outB + (size_t)(c0 + 3) * HW) = v;
  }
}

extern "C" void kernel_launch(void* const* d_in, const int* in_sizes, int n_in,
                              void* d_out, int out_size, void* d_ws, size_t ws_size,
                              hipStream_t stream) {
  const float* first  = (const float*)d_in[0];
  const float* second = (const float*)d_in[1];
  float* out = (float*)d_out;

  corr_transpose_kernel<<<dim3(NWG), 256, 0, stream>>>(first, second, out);
}

// Round 10
// 107.685 us; speedup vs baseline: 1.7987x; 1.1690x over previous
//
#include <hip/hip_runtime.h>

#define MD 4
#define DD 9          // 2*MD+1
#define KK 81         // DD*DD
#define B_ 4
#define C_ 128
#define H_ 192
#define W_ 192
#define HW (H_ * W_)
#define NWG 4608      // 2 chalf * 3 xt * 192 y * 4 b
#define PER_XCD (NWG / 8)

// out[b,c,y,x] = (1/C) * sum_{p,o} first[b,p*9+o,y,x] * second[b,c,y+p-4,x+o-4]
//
// Round 10: NO LDS, NO __syncthreads. Root issue across r1-r9 was never the
// schedule: OccupancyPercent sat at 29-40% in EVERY round (2-3 blocks/CU),
// because 4 waves were lockstep-coupled behind a 20.5KB LDS slab + barrier,
// so load->use latency was exposed and intra-thread pipelines (r4-r9) were
// fragile compiler-mood artifacts. Fix: each wave fully independent.
//  - first weights read per-p straight from global (9 float4; uniform across
//    cg -> broadcast; first is L3-resident 48MB, L1-side volume ~95MB).
//  - second windows as round 4: clamped loads + edge cndmask zeroing
//    (proven at 90.6us, absmax 9.8e-4).
//  - Occupancy now VGPR-limited only: ~7-8 waves/SIMD of phase-drifted
//    independent waves hide L2 latency by TLP, no scheduler cooperation
//    needed. Sentinels: LDS_Block_Size == 0, Occupancy > 55%,
//    WRITE_SIZE == 73728 KB exactly (spill alarm).

__device__ __forceinline__ void unpack12(float (&s)[12],
                                         const float4& A, const float4& M,
                                         const float4& E,
                                         bool edge, bool mA, bool mE) {
  s[0] = A.x; s[1] = A.y; s[2]  = A.z; s[3]  = A.w;
  s[4] = M.x; s[5] = M.y; s[6]  = M.z; s[7]  = M.w;
  s[8] = E.x; s[9] = E.y; s[10] = E.z; s[11] = E.w;
  if (edge) {                       // block-uniform branch; cndmask inside
    if (!mA) { s[0] = 0.f; s[1] = 0.f; s[2]  = 0.f; s[3]  = 0.f; }
    if (!mE) { s[8] = 0.f; s[9] = 0.f; s[10] = 0.f; s[11] = 0.f; }
  }
}

#define FMA_GROUP(accp, s)                                   \
  _Pragma("unroll")                                          \
  for (int o = 0; o < DD; ++o) {                             \
    accp[0] = fmaf(fo[o].x, s[o + 0], accp[0]);              \
    accp[1] = fmaf(fo[o].y, s[o + 1], accp[1]);              \
    accp[2] = fmaf(fo[o].z, s[o + 2], accp[2]);              \
    accp[3] = fmaf(fo[o].w, s[o + 3], accp[3]);              \
  }

__global__ __launch_bounds__(256)
void corr_transpose_kernel(const float* __restrict__ first,
                           const float* __restrict__ second,
                           float* __restrict__ out) {
  // bijective XCD swizzle (4608 % 8 == 0), y-fastest within an XCD chunk
  const int lin = blockIdx.x;
  const int wid = (lin & 7) * PER_XCD + (lin >> 3);
  const int y     = wid % H_;
  const int t     = wid / H_;          // 0..23
  const int chalf = t & 1;
  const int xt0   = ((t >> 1) % 3) * 64;
  const int b     = t / 6;

  const int tid = threadIdx.x;
  const int xg = tid & 15;
  const int cg = tid >> 4;
  const int c0 = chalf * 64 + cg * 4;
  const int x0 = xt0 + xg * 4;

  // clamped window offsets + masks (OOB regions are whole float4s)
  const bool mA = (x0 != 0);
  const bool mE = (x0 + 8 <= W_);
  const int  oa = mA ? x0 - 4 : 0;
  const int  oe = mE ? x0 + 4 : W_ - 8;
  const bool edge = (xt0 != 64);       // block-uniform

  // p-loop bounds hoisted (block-uniform)
  const int pstart = (y >= MD) ? 0 : (MD - y);
  const int pend   = (y + MD < H_) ? DD : (H_ + MD - y);
  const int yy0    = y + pstart - MD;

  // weight pointer: first[b, k = pstart*9, y, x0]; walks by HW per k
  const float* fp =
      first + ((size_t)(b * KK + pstart * DD) * H_ + y) * (size_t)W_ + x0;

  const float* secB = second + (size_t)b * C_ * HW;
  const float* rp0 = secB + ((size_t)c0 * H_ + yy0) * (size_t)W_;
  const float* rp1 = rp0 + HW;
  const float* rp2 = rp1 + HW;
  const float* rp3 = rp2 + HW;

  float acc0[4] = {0.f, 0.f, 0.f, 0.f};
  float acc1[4] = {0.f, 0.f, 0.f, 0.f};
  float acc2[4] = {0.f, 0.f, 0.f, 0.f};
  float acc3[4] = {0.f, 0.f, 0.f, 0.f};

  for (int p = pstart; p < pend; ++p) {
    // weights for this p: 9 float4 from global (broadcast across cg; L1/L2)
    float4 fo[DD];
#pragma unroll
    for (int o = 0; o < DD; ++o) {
      fo[o] = *reinterpret_cast<const float4*>(fp);
      fp += HW;
    }

    // channel windows for this p (loads clamped in-bounds; masked in unpack)
    float4 A0 = *reinterpret_cast<const float4*>(rp0 + oa);
    float4 M0 = *reinterpret_cast<const float4*>(rp0 + x0);
    float4 E0 = *reinterpret_cast<const float4*>(rp0 + oe);
    float4 A1 = *reinterpret_cast<const float4*>(rp1 + oa);
    float4 M1 = *reinterpret_cast<const float4*>(rp1 + x0);
    float4 E1 = *reinterpret_cast<const float4*>(rp1 + oe);
    float4 A2 = *reinterpret_cast<const float4*>(rp2 + oa);
    float4 M2 = *reinterpret_cast<const float4*>(rp2 + x0);
    float4 E2 = *reinterpret_cast<const float4*>(rp2 + oe);
    float4 A3 = *reinterpret_cast<const float4*>(rp3 + oa);
    float4 M3 = *reinterpret_cast<const float4*>(rp3 + x0);
    float4 E3 = *reinterpret_cast<const float4*>(rp3 + oe);

    {
      float s[12];
      unpack12(s, A0, M0, E0, edge, mA, mE);
      FMA_GROUP(acc0, s);
    }
    {
      float s[12];
      unpack12(s, A1, M1, E1, edge, mA, mE);
      FMA_GROUP(acc1, s);
    }
    {
      float s[12];
      unpack12(s, A2, M2, E2, edge, mA, mE);
      FMA_GROUP(acc2, s);
    }
    {
      float s[12];
      unpack12(s, A3, M3, E3, edge, mA, mE);
      FMA_GROUP(acc3, s);
    }

    rp0 += W_; rp1 += W_; rp2 += W_; rp3 += W_;
  }

  const float inv_c = 1.0f / (float)C_;
  float* outB = out + (size_t)b * C_ * HW + (size_t)y * W_ + x0;
  {
    float4 v;
    v.x = acc0[0] * inv_c; v.y = acc0[1] * inv_c;
    v.z = acc0[2] * inv_c; v.w = acc0[3] * inv_c;
    *reinterpret_cast<float4*>(outB + (size_t)(c0 + 0) * HW) = v;
    v.x = acc1[0] * inv_c; v.y = acc1[1] * inv_c;
    v.z = acc1[2] * inv_c; v.w = acc1[3] * inv_c;
    *reinterpret_cast<float4*>(outB + (size_t)(c0 + 1) * HW) = v;
    v.x = acc2[0] * inv_c; v.y = acc2[1] * inv_c;
    v.z = acc2[2] * inv_c; v.w = acc2[3] * inv_c;
    *reinterpret_cast<float4*>(outB + (size_t)(c0 + 2) * HW) = v;
    v.x = acc3[0] * inv_c; v.y = acc3[1] * inv_c;
    v.z = acc3[2] * inv_c; v.w = acc3[3] * inv_c;
    *reinterpret_cast<float4*>(outB + (size_t)(c0 + 3) * HW) = v;
  }
}

extern "C" void kernel_launch(void* const* d_in, const int* in_sizes, int n_in,
                              void* d_out, int out_size, void* d_ws, size_t ws_size,
                              hipStream_t stream) {
  const float* first  = (const float*)d_in[0];
  const float* second = (const float*)d_in[1];
  float* out = (float*)d_out;

  corr_transpose_kernel<<<dim3(NWG), 256, 0, stream>>>(first, second, out);
}